// Round 10
// baseline (11163.024 us; speedup 1.0000x reference)
//
#include <hip/hip_runtime.h>

// ---------------------------------------------------------------------------
// 3-layer LayerNorm-GRU (haste style), B=32 T=512 IN=128 H=1024 OUT=80
// Round 16: R15 protocol (proven 3357us/layer) + rotating virgin buffers.
//   Hidden cost identified: 12MB/step of LLC-port traffic — all 128 blocks
//   re-read full h (64KB) + pstat (32KB) via sc0sc1 BYPASS loads, skipping
//   the XCD L2s entirely (16 blocks/XCD refetch identical lines from LLC).
//   Fix: publish h(t) -> hrot[t], stats -> prot[t] (sc1 write-through,
//   full-line writes, same as before) but READ with plain cached loads.
//   Addresses are virgin each step => L2 must miss => fetch from LLC =>
//   coherent with NO fence; concurrent same-line misses from an XCD's 16
//   blocks merge in L2 MSHRs => ~16x less LLC read traffic, L2-hit latency
//   for most af loads. Buffers reused across layers only (kernel-boundary
//   cache inv covers it — same mechanism the hf32 handoff already uses).
//   Protocol bit-identical to R15: 32-line sharded counters, tid<32 polls,
//   5 barriers/step, sc1 publish -> wave vmcnt(0) -> counter add.
// ---------------------------------------------------------------------------

typedef float    f32x4 __attribute__((ext_vector_type(4)));
typedef _Float16 f16x8 __attribute__((ext_vector_type(8)));

#define HH      1024
#define TT      512
#define BBATCH  32
#define H3      3072
#define MROWS   16384      // B*T
#define NBLK_R  128        // compute blocks
#define HPB     8          // h-indices per recurrence block
#define COLS    24         // 3*HPB columns of R per block
#define LN_EPS  1e-5f

// workspace layout (bytes)
#define OFF_CTRL   0u                 // cntA 32 lines @0, cntB 32 lines @4096
#define OFF_HF     8192u              // h fp32 [32][1024] = 128 KB (ends 139264)
#define CTRL_BYTES 139264u            // memset region (counters + hf32)
#define OFF_WLB    327680u            // Wlin^T fp16 [80][1024]  = 160 KB
#define OFF_WB     524288u            // W^T fp16 [3072][K<=1024] = 6 MB
#define OFF_XBF    (8ull<<20)         // x fp16 [16384][128]     = 4 MB
#define OFF_WX     (16ull<<20)        // wx fp16 [16384][3072]   = 96 MB
#define OFF_HSA    (112ull<<20)       // hs fp16 [16384][1024]   = 32 MB
#define OFF_HSB    (144ull<<20)       // hs fp16 [16384][1024]   = 32 MB (end 176 MB)
#define OFF_HROT   (176ull<<20)       // h rotating [513][128][32][8B] = 33.6 MB
#define OFF_PROT   (212ull<<20)       // pstat rotating [512][128][64] f32 = 16 MB (end 228 MB)

#define ALOAD(p)    __hip_atomic_load((p),  __ATOMIC_RELAXED, __HIP_MEMORY_SCOPE_AGENT)
#define ASTORE(p,v) __hip_atomic_store((p), (v), __ATOMIC_RELAXED, __HIP_MEMORY_SCOPE_AGENT)
#define AADD(p)     __hip_atomic_fetch_add((p), 1u, __ATOMIC_RELAXED, __HIP_MEMORY_SCOPE_AGENT)

__device__ __forceinline__ float sigf(float x) {
  return __builtin_amdgcn_rcpf(1.f + __expf(-x));
}
__device__ __forceinline__ float tanhfast(float x) {
  const float e2 = __expf(2.f * x);
  return 1.f - 2.f * __builtin_amdgcn_rcpf(e2 + 1.f);
}

// ---------------------------------------------------------------------------
// init: x fp32 -> fp16 ; Wlin [1024][80] -> Wlb^T fp16 [80][1024]
__global__ __launch_bounds__(256, 1) void k_init(
    const float* __restrict__ x, _Float16* __restrict__ xb,
    const float* __restrict__ Wlin, _Float16* __restrict__ Wlb)
{
  const size_t stride = (size_t)gridDim.x * 256;
  for (size_t i = (size_t)blockIdx.x * 256 + threadIdx.x; i < (size_t)MROWS * 128; i += stride)
    xb[i] = (_Float16)x[i];
  for (size_t i = (size_t)blockIdx.x * 256 + threadIdx.x; i < 80u * 1024u; i += stride) {
    const size_t n = i >> 10, k = i & 1023u;
    Wlb[i] = (_Float16)Wlin[k * 80 + n];
  }
}

// W fp32 [K][3072] -> Wb fp16 [3072][K] (n-major for B-fragments)
__global__ __launch_bounds__(256, 1) void k_convW(
    const float* __restrict__ W, _Float16* __restrict__ Wb, const int K)
{
  const int n = blockIdx.x;
  for (int k = threadIdx.x; k < K; k += 256)
    Wb[(size_t)n * K + k] = (_Float16)W[(size_t)k * H3 + n];
}

// Cw[16384][3072] (fp16, raw pre-LN) = A[16384][K] @ W[K][3072]
__global__ __launch_bounds__(256, 1) void k_gemm(
    const _Float16* __restrict__ A,
    const _Float16* __restrict__ Bw,   // [3072][K]
    _Float16* __restrict__ Cw,
    const int K)
{
  __shared__ _Float16 Bs[64][40];
  const int tid = threadIdx.x;
  const int lane = tid & 63, wv = tid >> 6;
  const int l15 = lane & 15, quad = lane >> 4;
  const int tilem = blockIdx.x / 48, tilen = blockIdx.x % 48;
  const int mbase = tilem * 64 + wv * 16;
  const size_t nbase = (size_t)tilen * 64;
  f32x4 acc[4] = {{0.f,0.f,0.f,0.f},{0.f,0.f,0.f,0.f},{0.f,0.f,0.f,0.f},{0.f,0.f,0.f,0.f}};
  const _Float16* arow = A + (size_t)(mbase + l15) * K + quad * 8;
  const int sn = tid >> 2, sk = (tid & 3) * 8;
  const _Float16* bsrc = Bw + (nbase + sn) * K + sk;
  for (int kc = 0; kc < K; kc += 32) {
    __syncthreads();
    *(f16x8*)(&Bs[sn][sk]) = *(const f16x8*)(bsrc + kc);
    __syncthreads();
    const f16x8 af = *(const f16x8*)(arow + kc);
#pragma unroll
    for (int nt = 0; nt < 4; ++nt) {
      const f16x8 bv = *(const f16x8*)(&Bs[nt * 16 + l15][quad * 8]);
      acc[nt] = __builtin_amdgcn_mfma_f32_16x16x32_f16(af, bv, acc[nt], 0, 0, 0);
    }
  }
#pragma unroll
  for (int nt = 0; nt < 4; ++nt)
#pragma unroll
    for (int j = 0; j < 4; ++j)
      Cw[(size_t)(mbase + quad * 4 + j) * H3 + nbase + nt * 16 + l15] = (_Float16)acc[nt][j];
}

// in-place LayerNorm * gw over rows of wx (3072 cols), one row per wave
__global__ __launch_bounds__(256, 1) void k_ln(
    _Float16* __restrict__ wxp, const float* __restrict__ gw)
{
  const int wv = threadIdx.x >> 6, lane = threadIdx.x & 63;
  const size_t row = (size_t)blockIdx.x * 4 + wv;
  _Float16* p = wxp + row * H3 + lane * 8;
  float vals[48];
  float s = 0.f, q = 0.f;
#pragma unroll
  for (int c = 0; c < 6; ++c) {
    const f16x8 v = *(const f16x8*)(p + c * 512);
#pragma unroll
    for (int j = 0; j < 8; ++j) {
      const float f = (float)v[j];
      vals[c * 8 + j] = f; s += f; q += f * f;
    }
  }
#pragma unroll
  for (int m = 1; m < 64; m <<= 1) { s += __shfl_xor(s, m); q += __shfl_xor(q, m); }
  const float mean = s * (1.f / H3);
  const float var  = q * (1.f / H3) - mean * mean;
  const float inv  = rsqrtf(var + LN_EPS);
#pragma unroll
  for (int c = 0; c < 6; ++c) {
    f16x8 o;
#pragma unroll
    for (int j = 0; j < 8; ++j)
      o[j] = (_Float16)((vals[c * 8 + j] - mean) * inv * gw[c * 512 + lane * 8 + j]);
    *(f16x8*)(p + c * 512) = o;
  }
}

// ---------------------------------------------------------------------------
// recurrence: 512 steps, 128 blocks, R15 protocol, rotating virgin buffers
__global__ __launch_bounds__(256, 1) void k_recur(
    const float* __restrict__ R, const float* __restrict__ bx,
    const float* __restrict__ br, const float* __restrict__ gr,
    const _Float16* __restrict__ wx,
    _Float16* __restrict__ hs_out,
    unsigned* __restrict__ hrot,      // rotating h: [513][128 blk][32 row][4 u32]
    float* __restrict__ hf32,
    float* __restrict__ prot,         // rotating pstat: [512][128][64] f32
    unsigned* __restrict__ ctrl,
    const unsigned abase,             // l*TT
    const unsigned hbase)             // l*(TT+1)
{
  const int tid = threadIdx.x;
  const int blk = blockIdx.x;
  unsigned* cntA = ctrl;              // 32 lines, word stride 32 (4 adds/line)
  unsigned* cntB = ctrl + 1024;       // 32 lines, word stride 32 (16 adds/line)

  __shared__ _Float16 Rs[COLS][HH + 8];
  __shared__ float rhp[2][BBATCH][27];    // K-half partials (odd stride)
  __shared__ float statb[BBATCH][2];
  __shared__ float pred[16][68];          // pstat row-group partials

  const int lane = tid & 63;
  const int wv   = tid >> 6;
  const int mh   = wv >> 1;       // which 16 batch rows
  const int kh   = wv & 1;        // which K half (512)
  const int l15  = lane & 15;
  const int quad = lane >> 4;
  const int kb   = kh * 512;
  const int lineB = ((blk & 7) * 4 + wv) * 32;   // cntB shard for this wave

  // load R slice (cols {i, H+i, 2H+i} for i in [blk*8, blk*8+8)), fp32->fp16
  for (int n = 0; n < COLS; ++n) {
    const int gc = (n >> 3) * HH + blk * HPB + (n & 7);
    for (int k = tid; k < HH; k += 256)
      Rs[n][k] = (_Float16)R[(size_t)k * H3 + gc];
  }

  // per-thread gate ownership: (batch row, h-index)
  const int b_row = tid >> 3;
  const int jj    = tid & 7;
  const int gi    = blk * HPB + jj;
  const float bxz = bx[gi], bxr = bx[HH + gi], bxg = bx[2 * HH + gi];
  const float brz = br[gi], brr = br[HH + gi], brg = br[2 * HH + gi];
  const float grz = gr[gi], grr = gr[HH + gi], grg = gr[2 * HH + gi];
  float hloc = hf32[b_row * HH + gi];

  // initial coherent publish of h(0) into rotating buffer 0 (full-line sc1)
  {
    union { _Float16 f; unsigned short s; } hc; hc.f = (_Float16)hloc;
    const unsigned short mybits = hc.s;
    const unsigned short pbits  = (unsigned short)__shfl_xor((int)mybits, 1);
    if ((jj & 1) == 0) {
      const unsigned w = (unsigned)mybits | ((unsigned)pbits << 16);
      ASTORE(&hrot[blk * 128 + b_row * 4 + (jj >> 1)], w);
    }
  }
  asm volatile("s_waitcnt vmcnt(0)" ::: "memory");   // wave-local drain
  if (lane == 0) AADD(&cntB[lineB]);

  // consumer offset within a buffer: chunk (kh*64+quad), row (mh*16+l15)
  const size_t hoff = (size_t)(kh * 64 + quad) * 256 + (size_t)(mh * 16 + l15) * 8;

  for (int t = 0; t < TT; ++t) {
    // prefetch phase-2 wx operands (t-only dependence; L2-resident)
    const _Float16* wrow = wx + (size_t)(b_row * TT + t) * H3;
    const float wz = (float)wrow[gi];
    const float wr = (float)wrow[HH + gi];
    const float wg = (float)wrow[2 * HH + gi];

    // ---- wait for all 512 wave h-publishes (32 sharded lines, tight poll)
    if (tid < 32) {
      const unsigned* p = cntB + tid * 32;
      const unsigned tgt = 16u * (hbase + (unsigned)t + 1u);
      int spins = 0;
      while (ALOAD(p) < tgt) { if (++spins > (1 << 24)) break; }
    }
    __syncthreads();                                   // barrier 1

    // ---- phase 1: 16 cached loads from virgin buffer t (L2-shared per XCD)
    const _Float16* hb = (const _Float16*)hrot + (size_t)t * 32768 + hoff;
    f16x8 af[16];
#pragma unroll
    for (int ks = 0; ks < 16; ++ks)
      af[ks] = *(const f16x8*)(hb + ks * 1024);        // +4 blocks per ks
    f32x4 acc0 = {0.f,0.f,0.f,0.f}, acc1 = {0.f,0.f,0.f,0.f};
#pragma unroll
    for (int ks = 0; ks < 16; ++ks) {
      const f16x8 b0 = *(const f16x8*)(&Rs[l15][kb + ks * 32 + quad * 8]);
      acc0 = __builtin_amdgcn_mfma_f32_16x16x32_f16(af[ks], b0, acc0, 0, 0, 0);
      const int n1 = 16 + (l15 & 7);
      const f16x8 b1 = *(const f16x8*)(&Rs[n1][kb + ks * 32 + quad * 8]);
      acc1 = __builtin_amdgcn_mfma_f32_16x16x32_f16(af[ks], b1, acc1, 0, 0, 0);
    }
    // write K-half partials (C layout: row=quad*4+j, col=l15)
#pragma unroll
    for (int j = 0; j < 4; ++j) {
      rhp[kh][mh * 16 + quad * 4 + j][l15] = acc0[j];
      if (l15 < 8) rhp[kh][mh * 16 + quad * 4 + j][16 + l15] = acc1[j];
    }
    __syncthreads();                                   // barrier 2

    // ---- combine K halves; per-row LN partial stats (8-thread shfl reduce)
    const float rz = rhp[0][b_row][jj]      + rhp[1][b_row][jj];
    const float rr = rhp[0][b_row][8 + jj]  + rhp[1][b_row][8 + jj];
    const float rg = rhp[0][b_row][16 + jj] + rhp[1][b_row][16 + jj];
    {
      float s = rz + rr + rg;
      float q = rz * rz + rr * rr + rg * rg;
      s += __shfl_xor(s, 1); q += __shfl_xor(q, 1);
      s += __shfl_xor(s, 2); q += __shfl_xor(q, 2);
      s += __shfl_xor(s, 4); q += __shfl_xor(q, 4);
      if (jj == 0) { statb[b_row][0] = s; statb[b_row][1] = q; }
    }
    __syncthreads();                                   // barrier 3
    // publish pstat into rotating buffer t (wave 0 only; drain orders add)
    if (tid < 64) ASTORE(&prot[(size_t)t * 8192 + blk * 64 + tid],
                         statb[tid >> 1][tid & 1]);
    asm volatile("s_waitcnt vmcnt(0)" ::: "memory");
    if (tid == 0) AADD(&cntA[(blk & 31) * 32]);

    // ---- wait for all 128 pstat publishes (32 sharded lines)
    if (tid < 32) {
      const unsigned* p = cntA + tid * 32;
      const unsigned tgt = 4u * (abase + (unsigned)t + 1u);
      int spins = 0;
      while (ALOAD(p) < tgt) { if (++spins > (1 << 24)) break; }
    }
    __syncthreads();                                   // barrier 4

    // ---- flat allreduce: 8 coalesced cached dwordx4 loads (virgin buffer)
    {
      const float* pb = prot + (size_t)t * 8192;
      const int prow0 = tid >> 4;          // 0..15
      const int pcol  = (tid & 15) * 4;    // 0..60
      const f32x4 pv0 = *(const f32x4*)(pb + (size_t)(prow0      ) * 64 + pcol);
      const f32x4 pv1 = *(const f32x4*)(pb + (size_t)(prow0 +  16) * 64 + pcol);
      const f32x4 pv2 = *(const f32x4*)(pb + (size_t)(prow0 +  32) * 64 + pcol);
      const f32x4 pv3 = *(const f32x4*)(pb + (size_t)(prow0 +  48) * 64 + pcol);
      const f32x4 pv4 = *(const f32x4*)(pb + (size_t)(prow0 +  64) * 64 + pcol);
      const f32x4 pv5 = *(const f32x4*)(pb + (size_t)(prow0 +  80) * 64 + pcol);
      const f32x4 pv6 = *(const f32x4*)(pb + (size_t)(prow0 +  96) * 64 + pcol);
      const f32x4 pv7 = *(const f32x4*)(pb + (size_t)(prow0 + 112) * 64 + pcol);
      const f32x4 pa = ((pv0 + pv1) + (pv2 + pv3)) + ((pv4 + pv5) + (pv6 + pv7));
      *(f32x4*)(&pred[prow0][pcol]) = pa;
    }
    __syncthreads();                                   // barrier 5
    // broadcast-read finish: 16 group-partials for own row (same-addr bcast)
    float sfs = 0.f, sfq = 0.f;
#pragma unroll
    for (int g = 0; g < 16; ++g) {
      sfs += pred[g][2 * b_row];
      sfq += pred[g][2 * b_row + 1];
    }

    // ---- phase 2: finalize LN, gates, h update
    const float mean = sfs * (1.f / H3);
    const float var  = sfq * (1.f / H3) - mean * mean;
    const float inv  = __frsqrt_rn(var + LN_EPS);
    const float rzn = (rz - mean) * inv * grz;
    const float rrn = (rr - mean) * inv * grr;
    const float rgn = (rg - mean) * inv * grg;
    const float zg    = sigf(wz + bxz + rzn + brz);
    const float rgate = sigf(wr + bxr + rrn + brr);
    const float gg    = tanhfast(wg + bxg + rgate * (rgn + brg));
    const float hn = zg * hloc + (1.f - zg) * gg;
    hloc = hn;
    union { _Float16 f; unsigned short s; } hc; hc.f = (_Float16)hn;
    const unsigned short mybits = hc.s;
    const unsigned short pbits  = (unsigned short)__shfl_xor((int)mybits, 1);
    if ((jj & 1) == 0) {
      const unsigned w = (unsigned)mybits | ((unsigned)pbits << 16);
      ASTORE(&hrot[(size_t)(t + 1) * 16384 + blk * 128 + b_row * 4 + (jj >> 1)], w);
    }
    hs_out[(size_t)(b_row * TT + t) * HH + gi] = hc.f;        // L2-cached
    asm volatile("s_waitcnt vmcnt(0)" ::: "memory");          // wave-local drain
    if (lane == 0) AADD(&cntB[lineB]);                        // per-wave flag
  }
  hf32[b_row * HH + gi] = hloc;   // fp32 handoff to next layer (cached)
}

// ---------------------------------------------------------------------------
// out[16384][80] = tanh(hs @ Wlin + blin)
__global__ __launch_bounds__(256, 1) void k_proj(
    const _Float16* __restrict__ hs,
    const _Float16* __restrict__ Wlb,   // [80][1024] fp16
    const float* __restrict__ blin,
    float* __restrict__ out)
{
  const int tid = threadIdx.x, lane = tid & 63, wv = tid >> 6;
  const int l15 = lane & 15, quad = lane >> 4;
  const int mbase = blockIdx.x * 64 + wv * 16;
  f32x4 acc[5] = {{0.f,0.f,0.f,0.f},{0.f,0.f,0.f,0.f},{0.f,0.f,0.f,0.f},
                  {0.f,0.f,0.f,0.f},{0.f,0.f,0.f,0.f}};
  const _Float16* arow = hs + (size_t)(mbase + l15) * HH + quad * 8;
  for (int kc = 0; kc < HH; kc += 32) {
    const f16x8 af = *(const f16x8*)(arow + kc);
#pragma unroll
    for (int nt = 0; nt < 5; ++nt) {
      const f16x8 bv = *(const f16x8*)(Wlb + (size_t)(nt * 16 + l15) * HH + kc + quad * 8);
      acc[nt] = __builtin_amdgcn_mfma_f32_16x16x32_f16(af, bv, acc[nt], 0, 0, 0);
    }
  }
#pragma unroll
  for (int nt = 0; nt < 5; ++nt)
#pragma unroll
    for (int j = 0; j < 4; ++j) {
      const int col = nt * 16 + l15;
      out[(size_t)(mbase + quad * 4 + j) * 80 + col] = tanhf(acc[nt][j] + blin[col]);
    }
}

// ---------------------------------------------------------------------------
extern "C" void kernel_launch(void* const* d_in, const int* in_sizes, int n_in,
                              void* d_out, int out_size, void* d_ws, size_t ws_size,
                              hipStream_t stream)
{
  const float* x    = (const float*)d_in[0];
  const float* W0   = (const float*)d_in[1];
  const float* R0   = (const float*)d_in[2];
  const float* bx0  = (const float*)d_in[3];
  const float* br0  = (const float*)d_in[4];
  const float* gw0  = (const float*)d_in[5];
  const float* gr0  = (const float*)d_in[6];
  const float* Wk   = (const float*)d_in[7];
  const float* Rk   = (const float*)d_in[8];
  const float* bxk  = (const float*)d_in[9];
  const float* brk  = (const float*)d_in[10];
  const float* gwk  = (const float*)d_in[11];
  const float* grk  = (const float*)d_in[12];
  const float* Wlin = (const float*)d_in[13];
  const float* blin = (const float*)d_in[14];

  char* ws = (char*)d_ws;
  unsigned*  ctrl   = (unsigned*)(ws + OFF_CTRL);
  float*     hf32   = (float*)(ws + OFF_HF);
  _Float16*  Wlb    = (_Float16*)(ws + OFF_WLB);
  _Float16*  Wb     = (_Float16*)(ws + OFF_WB);
  _Float16*  xb     = (_Float16*)(ws + OFF_XBF);
  _Float16*  wx     = (_Float16*)(ws + OFF_WX);
  _Float16*  hsA    = (_Float16*)(ws + OFF_HSA);
  _Float16*  hsB    = (_Float16*)(ws + OFF_HSB);
  unsigned*  hrot   = (unsigned*)(ws + OFF_HROT);
  float*     prot   = (float*)(ws + OFF_PROT);

  hipMemsetAsync(d_ws, 0, CTRL_BYTES, stream);   // counters + hf32

  k_init<<<2048, 256, 0, stream>>>(x, xb, Wlin, Wlb);

  for (int l = 0; l < 3; ++l) {
    const int K = l ? HH : 128;
    const float* Wl  = l ? (Wk  + (size_t)(l - 1) * HH * H3) : W0;
    const float* Rl  = l ? (Rk  + (size_t)(l - 1) * HH * H3) : R0;
    const float* bxl = l ? (bxk + (size_t)(l - 1) * H3) : bx0;
    const float* brl = l ? (brk + (size_t)(l - 1) * H3) : br0;
    const float* gwl = l ? (gwk + (size_t)(l - 1) * H3) : gw0;
    const float* grl = l ? (grk + (size_t)(l - 1) * H3) : gr0;
    const _Float16* Ain = (l == 0) ? xb : ((l == 1) ? hsA : hsB);
    _Float16* hs_out = (l == 1) ? hsB : hsA;

    k_convW<<<H3, 256, 0, stream>>>(Wl, Wb, K);
    k_gemm<<<12288, 256, 0, stream>>>(Ain, Wb, wx, K);
    k_ln<<<4096, 256, 0, stream>>>(wx, gwl);
    k_recur<<<NBLK_R, 256, 0, stream>>>(Rl, bxl, brl, grl, wx, hs_out,
                                        hrot, hf32, prot, ctrl,
                                        (unsigned)l * (unsigned)TT,
                                        (unsigned)l * (TT + 1u));
  }
  k_proj<<<256, 256, 0, stream>>>(hsA, Wlb, blin, (float*)d_out);
}